// Round 1
// baseline (303.736 us; speedup 1.0000x reference)
//
#include <hip/hip_runtime.h>

// VQ-VAE vector quantization, fp32 exact.
// N = 131072 queries (D=64), up to 1024 codes.
// ws layout (floats): [0] loss accum, [1024..2047] -0.5*||c||^2, [2048..3071] counts.

#define TQ 128
#define NBLK 1024  // N / TQ

__global__ void vq_zero(float* ws) {
  const int t = threadIdx.x;  // 1024 threads
  ws[2048 + t] = 0.0f;
  if (t == 0) ws[0] = 0.0f;
}

__global__ void vq_norms(const float* __restrict__ cb0, const float* __restrict__ cb1,
                         float* __restrict__ nhn) {
  const int c = blockIdx.x * 256 + threadIdx.x;  // 4 blocks -> 1024
  const float* row = (c < 512) ? (cb0 + (size_t)c * 64) : (cb1 + (size_t)(c - 512) * 64);
  float s = 0.f;
#pragma unroll
  for (int d = 0; d < 64; d += 4) {
    const float4 v = *(const float4*)(row + d);
    s += v.x * v.x + v.y * v.y + v.z * v.z + v.w * v.w;
  }
  nhn[c] = -0.5f * s;
}

__global__ __launch_bounds__(256) void vq_main(
    const float* __restrict__ xin, const float* __restrict__ cb0,
    const float* __restrict__ cb1, const int* __restrict__ idxp,
    const float* __restrict__ nhn, float* __restrict__ out,
    float* __restrict__ lossacc, float* __restrict__ counts) {
  __shared__ float xs[64 * 128];  // x tile [d][q]
  __shared__ float cs[64 * 128];  // code chunk [d][swizzled c]; reused as scratch in epilogue

  const int tid = threadIdx.x;
  const int nq0 = blockIdx.x * TQ;
  const int b = nq0 >> 12;     // batch (4096 queries per batch slab)
  const int hw0 = nq0 & 4095;  // offset within H*W
  const int NC = (*idxp == 0) ? 512 : 1024;

  // ---- stage x tile: [d][q], coalesced float4 rows
  {
    const int qg = (tid & 31) * 4;
    const int d0 = tid >> 5;
#pragma unroll
    for (int dd = d0; dd < 64; dd += 8) {
      const float4 v = *(const float4*)(xin + (((size_t)(b * 64 + dd)) << 12) + hw0 + qg);
      *(float4*)(xs + dd * 128 + qg) = v;
    }
  }

  const int tq = tid >> 4;  // 0..15 -> q rows tq*8..+7
  const int tc = tid & 15;  // 0..15 -> c cols tc*8..+7
  const int G0 = 2 * tc, G1 = 2 * tc + 1;
  const int s0b = G0 ^ (G0 >> 3);
  const int s1b = G1 ^ (G1 >> 3);

  float maxv[8];
  int mini[8];
#pragma unroll
  for (int i = 0; i < 8; ++i) { maxv[i] = -3.4e38f; mini[i] = 0; }

  const int nch = NC >> 7;
  for (int ch = 0; ch < nch; ++ch) {
    __syncthreads();  // previous chunk fully consumed (and xs staged, for ch==0)
    // ---- stage code chunk, transposed [d][c] with XOR swizzle:
    // element (d,c) at float index d*128 + (G ^ (G>>3) ^ ((d>>2)&7))*4 + (c&3), G=c>>2
    {
      const float* cbase = (ch < 4) ? (cb0 + (size_t)ch * (128 * 64))
                                    : (cb1 + (size_t)(ch - 4) * (128 * 64));
      const int lk = tid & 15;  // d-group: d = 4*lk..4*lk+3
      const int cg = tid >> 4;
#pragma unroll
      for (int it = 0; it < 8; ++it) {
        const int c = it * 16 + cg;
        const float4 v = *(const float4*)(cbase + (size_t)c * 64 + lk * 4);
        const int G = c >> 2;
        const int s = G ^ (G >> 3) ^ (lk & 7);
        float* p = cs + (lk * 4) * 128 + s * 4 + (c & 3);
        p[0] = v.x; p[128] = v.y; p[256] = v.z; p[384] = v.w;
      }
    }
    __syncthreads();

    // ---- acc[i][j] starts at -0.5*||c_j||^2, accumulates +x_i . c_j
    float acc[8][8];
    {
      const float* hn = nhn + ch * 128 + tc * 8;
      const float4 h0 = *(const float4*)(hn);
      const float4 h1 = *(const float4*)(hn + 4);
      const float hv[8] = {h0.x, h0.y, h0.z, h0.w, h1.x, h1.y, h1.z, h1.w};
#pragma unroll
      for (int i = 0; i < 8; ++i)
#pragma unroll
        for (int j = 0; j < 8; ++j) acc[i][j] = hv[j];
    }

#pragma unroll 2
    for (int k = 0; k < 16; ++k) {
      const int s0 = (s0b ^ (k & 7)) * 4;
      const int s1 = (s1b ^ (k & 7)) * 4;
#pragma unroll
      for (int m = 0; m < 4; ++m) {
        const int d = k * 4 + m;
        const float4 xa = *(const float4*)(xs + d * 128 + tq * 8);
        const float4 xb = *(const float4*)(xs + d * 128 + tq * 8 + 4);
        const float4 c0 = *(const float4*)(cs + d * 128 + s0);
        const float4 c1 = *(const float4*)(cs + d * 128 + s1);
        const float xv[8] = {xa.x, xa.y, xa.z, xa.w, xb.x, xb.y, xb.z, xb.w};
        const float cv[8] = {c0.x, c0.y, c0.z, c0.w, c1.x, c1.y, c1.z, c1.w};
#pragma unroll
        for (int i = 0; i < 8; ++i)
#pragma unroll
          for (int j = 0; j < 8; ++j) acc[i][j] += xv[i] * cv[j];
      }
    }

    // ---- running argmax update (strict >, ascending index => first-min semantics)
    const int cbase_idx = ch * 128 + tc * 8;
#pragma unroll
    for (int j = 0; j < 8; ++j) {
      const int cidx = cbase_idx + j;
#pragma unroll
      for (int i = 0; i < 8; ++i) {
        if (acc[i][j] > maxv[i]) { maxv[i] = acc[i][j]; mini[i] = cidx; }
      }
    }
  }

  // ---- reduce across the 16 tc lanes (same wave), tie -> smaller index
#pragma unroll
  for (int mk = 1; mk < 16; mk <<= 1) {
#pragma unroll
    for (int i = 0; i < 8; ++i) {
      const float ov = __shfl_xor(maxv[i], mk);
      const int oi = __shfl_xor(mini[i], mk);
      if (ov > maxv[i] || (ov == maxv[i] && oi < mini[i])) { maxv[i] = ov; mini[i] = oi; }
    }
  }

  __syncthreads();  // cs free for reuse
  float* xxs = cs;               // [128] ||x_q||^2
  int* qidx = (int*)(cs + 128);  // [128] chosen code per q
  float* red = cs + 256;         // [16] loss partials

  if (tc == 0) {
#pragma unroll
    for (int i = 0; i < 8; ++i) qidx[tq * 8 + i] = mini[i];
  }
  if (tid < 128) {
    float s = 0.f;
#pragma unroll 8
    for (int d = 0; d < 64; ++d) { const float v = xs[d * 128 + tid]; s += v * v; }
    xxs[tid] = s;
  }
  __syncthreads();

  if (tc == 0) {
    float ls = 0.f;
#pragma unroll
    for (int i = 0; i < 8; ++i) {
      ls += xxs[tq * 8 + i] - 2.0f * maxv[i];  // ||x||^2 - 2*(x.c* - 0.5||c*||^2) = ||x-c*||^2
      atomicAdd(&counts[mini[i]], 1.0f);
    }
    red[tq] = ls;
  }
  __syncthreads();
  if (tid == 0) {
    float s = 0.f;
#pragma unroll
    for (int i = 0; i < 16; ++i) s += red[i];
    atomicAdd(lossacc, s);
  }

  // ---- quantized output, NCHW, coalesced stores (code rows are L2-hot)
#pragma unroll 4
  for (int rep = 0; rep < 32; ++rep) {
    const int e = rep * 256 + tid;
    const int d = e >> 7;
    const int q = e & 127;
    const int ci = qidx[q];
    const float* crow = (ci < 512) ? (cb0 + (size_t)ci * 64) : (cb1 + (size_t)(ci - 512) * 64);
    out[(((size_t)(b * 64 + d)) << 12) + hw0 + q] = crow[d];
  }
}

__global__ void vq_final(const float* __restrict__ ws, float* __restrict__ out) {
  __shared__ float sred[256];
  const int t = threadIdx.x;
  float h = 0.f;
#pragma unroll
  for (int i = t; i < 1024; i += 256) {
    const float avg = ws[2048 + i] * (1.0f / 131072.0f);
    h += avg * logf(avg + 1e-10f);  // 0 bins contribute exactly 0
  }
  sred[t] = h;
  __syncthreads();
  for (int s2 = 128; s2 > 0; s2 >>= 1) {
    if (t < s2) sred[t] += sred[t + s2];
    __syncthreads();
  }
  if (t == 0) {
    out[8388608] = 1.25f * ws[0] * (1.0f / 8388608.0f);
    out[8388609] = expf(-sred[0]);
  }
}

extern "C" void kernel_launch(void* const* d_in, const int* in_sizes, int n_in,
                              void* d_out, int out_size, void* d_ws, size_t ws_size,
                              hipStream_t stream) {
  (void)in_sizes; (void)n_in; (void)out_size; (void)ws_size;
  const float* xin = (const float*)d_in[0];
  const float* cb0 = (const float*)d_in[1];
  const float* cb1 = (const float*)d_in[2];
  const int* idxp = (const int*)d_in[3];
  float* out = (float*)d_out;
  float* ws = (float*)d_ws;
  float* nhn = ws + 1024;
  float* counts = ws + 2048;

  vq_zero<<<1, 1024, 0, stream>>>(ws);
  vq_norms<<<4, 256, 0, stream>>>(cb0, cb1, nhn);
  vq_main<<<NBLK, 256, 0, stream>>>(xin, cb0, cb1, idxp, nhn, out, ws, counts);
  vq_final<<<1, 256, 0, stream>>>(ws, out);
}

// Round 2
// 128.968 us; speedup vs baseline: 2.3551x; 2.3551x over previous
//
#include <hip/hip_runtime.h>

// VQ-VAE vector quantization via bf16-split MFMA (x=xh+xl, c=ch+cl; score =
// xh.ch + xh.cl + xl.ch - 0.5||c||^2, error ~2^-18 relative).
// N = 131072 queries (D=64), up to 1024 codes.
// ws layout (floats): [0] loss, [1024..2047] nhn=-0.5||c||^2, [2048..3071] counts,
//                     [4096..69631] packed bf16 code tiles (1024 rows x 256B).

typedef __attribute__((ext_vector_type(8))) short short8;
typedef __attribute__((ext_vector_type(16))) float f32x16;

#define PACKED_OFF 4096

#define GLL16(gsrc, ldst)                                                      \
  __builtin_amdgcn_global_load_lds(                                            \
      (const __attribute__((address_space(1))) void*)(gsrc),                   \
      (__attribute__((address_space(3))) void*)(ldst), 16, 0, 0)

__device__ __forceinline__ unsigned short bf16_rne(float v, float& rest) {
  const unsigned u = __float_as_uint(v);
  const unsigned r = u + 0x7fffu + ((u >> 16) & 1u);
  const unsigned short h = (unsigned short)(r >> 16);
  rest = v - __uint_as_float((unsigned)h << 16);
  return h;
}

__global__ void vq_zero(float* ws) {
  const int t = threadIdx.x;  // 1024 threads
  ws[2048 + t] = 0.0f;
  if (t == 0) ws[0] = 0.0f;
}

// Pre-split codes into bf16 hi/lo, XOR-swizzled granules, + norms.
// Row c (256B): granule g in 0..15 holds kk=g*8..g*8+7 (kk<64: hi, else lo),
// stored at slot (g ^ (c&15)).
__global__ void vq_pack(const float* __restrict__ cb0, const float* __restrict__ cb1,
                        float* __restrict__ ws) {
  const int c = blockIdx.x * 256 + threadIdx.x;  // 0..1023
  const float* row = (c < 512) ? (cb0 + (size_t)c * 64) : (cb1 + (size_t)(c - 512) * 64);
  float v[64];
  float nrm = 0.f;
#pragma unroll
  for (int d = 0; d < 64; d += 4) {
    const float4 f = *(const float4*)(row + d);
    v[d] = f.x; v[d + 1] = f.y; v[d + 2] = f.z; v[d + 3] = f.w;
    nrm += f.x * f.x + f.y * f.y + f.z * f.z + f.w * f.w;
  }
  ws[1024 + c] = -0.5f * nrm;
  unsigned short hi[64], lo[64];
#pragma unroll
  for (int d = 0; d < 64; ++d) {
    float rest, dump;
    hi[d] = bf16_rne(v[d], rest);
    lo[d] = bf16_rne(rest, dump);
  }
  float* pbase = ws + PACKED_OFF + (size_t)c * 64;  // 64 floats = 256B per row
#pragma unroll
  for (int g = 0; g < 16; ++g) {
    short8 gr;
#pragma unroll
    for (int e = 0; e < 8; ++e)
      gr[e] = (short)((g < 8) ? hi[g * 8 + e] : lo[(g - 8) * 8 + e]);
    const int slot = g ^ (c & 15);
    *(short8*)(pbase + slot * 4) = gr;
  }
}

__global__ __launch_bounds__(256, 2) void vq_main(
    const float* __restrict__ xin, const float* __restrict__ cb0,
    const float* __restrict__ cb1, const int* __restrict__ idxp,
    float* __restrict__ out, float* __restrict__ ws) {
  __shared__ char smem[65536];
  const int tid = threadIdx.x;
  const int w = tid >> 6;       // wave 0..3
  const int l = tid & 63;       // lane
  const int half = l >> 5;
  const int col = l & 31;
  const int sw = col & 15;      // swizzle key (c&15 == col&15 since 32%16==0)
  const int blk = blockIdx.x;   // 512 blocks x 256 q
  const int bb = blk >> 4;
  const int hw0 = (blk & 15) << 8;
  const int nch = (*idxp == 0) ? 8 : 16;
  const float* nhn = ws + 1024;
  const float* packed = ws + PACKED_OFF;
  float* counts = ws + 2048;

  // ---- stage x fp32 tile [d=64][q=256] into LDS (coalesced both sides)
  float* xfp = (float*)smem;
  {
    const int qg = (tid & 63) << 2;
    const int dsub = tid >> 6;
#pragma unroll
    for (int p = 0; p < 16; ++p) {
      const int d = p * 4 + dsub;
      const float4 f = *(const float4*)(xin + (((size_t)(bb * 64 + d)) << 12) + hw0 + qg);
      *(float4*)(xfp + d * 256 + qg) = f;
    }
  }
  __syncthreads();

  // ---- extract A fragments (xh, xl) into registers + ||x||^2 per q-row
  short8 xh[2][4], xl[2][4];
  float xx[2];
#pragma unroll
  for (int m = 0; m < 2; ++m) {
    const int qloc = w * 64 + m * 32 + col;
    float s = 0.f;
#pragma unroll
    for (int kf = 0; kf < 4; ++kf) {
#pragma unroll
      for (int j = 0; j < 8; ++j) {
        const int d = kf * 16 + half * 8 + j;
        const float v = xfp[d * 256 + qloc];
        float rest, dump;
        xh[m][kf][j] = (short)bf16_rne(v, rest);
        xl[m][kf][j] = (short)bf16_rne(rest, dump);
        s += v * v;
      }
    }
    s += __shfl_xor(s, 32);  // lanes l and l^32 hold same q, complementary d
    xx[m] = s;
  }
  __syncthreads();  // xfp dead; B double-buffer takes [0,32KB)

  float best[2][16];
  int meta[2][16];
#pragma unroll
  for (int m = 0; m < 2; ++m)
#pragma unroll
    for (int r = 0; r < 16; ++r) { best[m][r] = -3.4e38f; meta[m][r] = 0; }

  // ---- stage: 16KB chunk (64 codes x 256B) via global_load_lds width=16
  auto stage = [&](int ch, int buf) {
    const float* src = packed + (size_t)ch * 4096 + w * 256 + l * 4;
    char* dstb = smem + buf * 16384 + w * 1024;  // wave-uniform LDS base
#pragma unroll
    for (int i = 0; i < 4; ++i) GLL16(src + i * 1024, dstb + i * 4096);
  };

  stage(0, 0);
  for (int ch = 0; ch < nch; ++ch) {
    __syncthreads();  // staged buf ready (barrier drains vmcnt); prev buf free
    if (ch + 1 < nch) stage(ch + 1, (ch + 1) & 1);
    const char* bufp = smem + (ch & 1) * 16384;
    const float nh0 = nhn[ch * 64 + col];
    const float nh1 = nhn[ch * 64 + 32 + col];

    f32x16 acc[2][2];
#pragma unroll
    for (int m = 0; m < 2; ++m)
#pragma unroll
      for (int n = 0; n < 2; ++n) acc[m][n] = (f32x16)0.0f;

#pragma unroll
    for (int kf = 0; kf < 4; ++kf) {
      short8 bh[2], bl[2];
      const int gh = kf * 2 + half;  // hi granule; lo granule = gh + 8
#pragma unroll
      for (int n = 0; n < 2; ++n) {
        const char* rp = bufp + (n * 32 + col) * 256;
        bh[n] = *(const short8*)(rp + ((gh ^ sw) << 4));
        bl[n] = *(const short8*)(rp + (((gh + 8) ^ sw) << 4));
      }
      // term 1: xh . ch
#pragma unroll
      for (int n = 0; n < 2; ++n) {
        acc[0][n] = __builtin_amdgcn_mfma_f32_32x32x16_bf16(xh[0][kf], bh[n], acc[0][n], 0, 0, 0);
        acc[1][n] = __builtin_amdgcn_mfma_f32_32x32x16_bf16(xh[1][kf], bh[n], acc[1][n], 0, 0, 0);
      }
      // term 2: xh . cl
#pragma unroll
      for (int n = 0; n < 2; ++n) {
        acc[0][n] = __builtin_amdgcn_mfma_f32_32x32x16_bf16(xh[0][kf], bl[n], acc[0][n], 0, 0, 0);
        acc[1][n] = __builtin_amdgcn_mfma_f32_32x32x16_bf16(xh[1][kf], bl[n], acc[1][n], 0, 0, 0);
      }
      // term 3: xl . ch
#pragma unroll
      for (int n = 0; n < 2; ++n) {
        acc[0][n] = __builtin_amdgcn_mfma_f32_32x32x16_bf16(xl[0][kf], bh[n], acc[0][n], 0, 0, 0);
        acc[1][n] = __builtin_amdgcn_mfma_f32_32x32x16_bf16(xl[1][kf], bh[n], acc[1][n], 0, 0, 0);
      }
    }

    // ---- running argmax of (x.c - 0.5||c||^2); meta = ch*2 + nf, col implicit
    const int mb = ch * 2;
#pragma unroll
    for (int m = 0; m < 2; ++m) {
#pragma unroll
      for (int r = 0; r < 16; ++r) {
        const float s0 = acc[m][0][r] + nh0;
        const float s1 = acc[m][1][r] + nh1;
        const bool t1 = s1 > s0;  // tie -> nf=0 (smaller index)
        const float v = t1 ? s1 : s0;
        const int mt = mb + (t1 ? 1 : 0);
        if (v > best[m][r]) { best[m][r] = v; meta[m][r] = mt; }  // tie -> earlier (smaller c)
      }
    }
  }

  // ---- final cross-lane argmax reduce (within 32-lane half), first-idx ties
  float ls = 0.f;
  int* qbest = (int*)(smem + 32768);  // xfp region, dead since prologue
#pragma unroll
  for (int m = 0; m < 2; ++m) {
#pragma unroll
    for (int r = 0; r < 16; ++r) {
      float v = best[m][r];
      int idx = meta[m][r] * 32 + col;
#pragma unroll
      for (int mk = 1; mk < 32; mk <<= 1) {
        const float ov = __shfl_xor(v, mk);
        const int oi = __shfl_xor(idx, mk);
        if (ov > v || (ov == v && oi < idx)) { v = ov; idx = oi; }
      }
      // owner lane of this q-row finalizes (row formula of 32x32 C layout)
      if (col == ((r & 3) + 8 * (r >> 2) + 4 * half)) {
        ls += xx[m] - 2.0f * v;  // ||x||^2 - 2(x.c* - 0.5||c*||^2) = ||x-c*||^2
        qbest[w * 64 + m * 32 + col] = idx;
      }
    }
  }
#pragma unroll
  for (int mk = 1; mk < 64; mk <<= 1) ls += __shfl_xor(ls, mk);
  if (l == 0) atomicAdd(ws, ls);
  __syncthreads();

  // ---- histogram + quantized output (NCHW, coalesced stores; codes L2-hot)
  const int ci = qbest[tid];
  atomicAdd(&counts[ci], 1.0f);
  const float* crow = (ci < 512) ? (cb0 + (size_t)ci * 64) : (cb1 + (size_t)(ci - 512) * 64);
  float cv[64];
#pragma unroll
  for (int d = 0; d < 64; d += 4) {
    const float4 f = *(const float4*)(crow + d);
    cv[d] = f.x; cv[d + 1] = f.y; cv[d + 2] = f.z; cv[d + 3] = f.w;
  }
  float* obase = out + (((size_t)(bb * 64)) << 12) + hw0 + tid;
#pragma unroll
  for (int d = 0; d < 64; ++d) obase[(size_t)d << 12] = cv[d];
}

__global__ void vq_final(const float* __restrict__ ws, float* __restrict__ out) {
  __shared__ float sred[256];
  const int t = threadIdx.x;
  float h = 0.f;
#pragma unroll
  for (int i = t; i < 1024; i += 256) {
    const float avg = ws[2048 + i] * (1.0f / 131072.0f);
    h += avg * logf(avg + 1e-10f);
  }
  sred[t] = h;
  __syncthreads();
  for (int s2 = 128; s2 > 0; s2 >>= 1) {
    if (t < s2) sred[t] += sred[t + s2];
    __syncthreads();
  }
  if (t == 0) {
    out[8388608] = 1.25f * ws[0] * (1.0f / 8388608.0f);
    out[8388609] = expf(-sred[0]);
  }
}

extern "C" void kernel_launch(void* const* d_in, const int* in_sizes, int n_in,
                              void* d_out, int out_size, void* d_ws, size_t ws_size,
                              hipStream_t stream) {
  (void)in_sizes; (void)n_in; (void)out_size; (void)ws_size;
  const float* xin = (const float*)d_in[0];
  const float* cb0 = (const float*)d_in[1];
  const float* cb1 = (const float*)d_in[2];
  const int* idxp = (const int*)d_in[3];
  float* out = (float*)d_out;
  float* ws = (float*)d_ws;

  vq_zero<<<1, 1024, 0, stream>>>(ws);
  vq_pack<<<4, 256, 0, stream>>>(cb0, cb1, ws);
  vq_main<<<512, 256, 0, stream>>>(xin, cb0, cb1, idxp, out, ws);
  vq_final<<<1, 256, 0, stream>>>(ws, out);
}

// Round 3
// 116.174 us; speedup vs baseline: 2.6145x; 1.1101x over previous
//
#include <hip/hip_runtime.h>

// VQ-VAE vector quantization via bf16-split MFMA (x=xh+xl, c=ch+cl; score =
// xh.ch + xh.cl + xl.ch - 0.5||c||^2, error ~2^-18 relative).
// N = 131072 queries (D=64), up to 1024 codes.
// ws layout (floats): [0] loss, [1024..2047] nhn=-0.5||c||^2, [2048..3071] counts,
//                     [4096..69631] packed bf16 code tiles (1024 rows x 256B).
// Round 3: q-tile 128, LDS 32KB (x tile reused as B dbuf), 1024 blocks = 4/CU.

typedef __attribute__((ext_vector_type(8))) short short8;
typedef __attribute__((ext_vector_type(16))) float f32x16;

#define PACKED_OFF 4096

#define GLL16(gsrc, ldst)                                                      \
  __builtin_amdgcn_global_load_lds(                                            \
      (const __attribute__((address_space(1))) void*)(gsrc),                   \
      (__attribute__((address_space(3))) void*)(ldst), 16, 0, 0)

__device__ __forceinline__ unsigned short bf16_rne(float v, float& rest) {
  const unsigned u = __float_as_uint(v);
  const unsigned r = u + 0x7fffu + ((u >> 16) & 1u);
  const unsigned short h = (unsigned short)(r >> 16);
  rest = v - __uint_as_float((unsigned)h << 16);
  return h;
}

// Pre-split codes into bf16 hi/lo XOR-swizzled granules + norms; zero accums.
// Row c (256B): granule g in 0..15 holds kk=g*8..g*8+7 (kk<64: hi, else lo),
// stored at slot (g ^ (c&15)).
__global__ void vq_pack(const float* __restrict__ cb0, const float* __restrict__ cb1,
                        float* __restrict__ ws) {
  const int c = blockIdx.x * 256 + threadIdx.x;  // 0..1023
  ws[2048 + c] = 0.0f;                           // counts
  if (c == 0) ws[0] = 0.0f;                      // loss
  const float* row = (c < 512) ? (cb0 + (size_t)c * 64) : (cb1 + (size_t)(c - 512) * 64);
  float v[64];
  float nrm = 0.f;
#pragma unroll
  for (int d = 0; d < 64; d += 4) {
    const float4 f = *(const float4*)(row + d);
    v[d] = f.x; v[d + 1] = f.y; v[d + 2] = f.z; v[d + 3] = f.w;
    nrm += f.x * f.x + f.y * f.y + f.z * f.z + f.w * f.w;
  }
  ws[1024 + c] = -0.5f * nrm;
  unsigned short hi[64], lo[64];
#pragma unroll
  for (int d = 0; d < 64; ++d) {
    float rest, dump;
    hi[d] = bf16_rne(v[d], rest);
    lo[d] = bf16_rne(rest, dump);
  }
  float* pbase = ws + PACKED_OFF + (size_t)c * 64;  // 64 floats = 256B per row
#pragma unroll
  for (int g = 0; g < 16; ++g) {
    short8 gr;
#pragma unroll
    for (int e = 0; e < 8; ++e)
      gr[e] = (short)((g < 8) ? hi[g * 8 + e] : lo[(g - 8) * 8 + e]);
    const int slot = g ^ (c & 15);
    *(short8*)(pbase + slot * 4) = gr;
  }
}

__global__ __launch_bounds__(256, 4) void vq_main(
    const float* __restrict__ xin, const float* __restrict__ cb0,
    const float* __restrict__ cb1, const int* __restrict__ idxp,
    float* __restrict__ out, float* __restrict__ ws) {
  __shared__ char smem[32768];
  const int tid = threadIdx.x;
  const int w = tid >> 6;      // wave 0..3, owns q rows w*32..+31
  const int l = tid & 63;
  const int half = l >> 5;
  const int col = l & 31;
  const int sw = col & 15;     // swizzle key
  const int blk = blockIdx.x;  // 1024 blocks x 128 q
  const int bb = blk >> 5;
  const int hw0 = (blk & 31) << 7;
  const int nch = (*idxp == 0) ? 8 : 16;
  const float* nhn = ws + 1024;
  const float* packed = ws + PACKED_OFF;
  float* counts = ws + 2048;

  // ---- stage x fp32 tile [d=64][q=128] into LDS (coalesced both sides)
  float* xfp = (float*)smem;
  {
    const int qg = (tid & 31) << 2;
    const int dsub = tid >> 5;  // 0..7
#pragma unroll
    for (int p = 0; p < 8; ++p) {
      const int d = p * 8 + dsub;
      const float4 f = *(const float4*)(xin + (((size_t)(bb * 64 + d)) << 12) + hw0 + qg);
      *(float4*)(xfp + d * 128 + qg) = f;
    }
  }
  __syncthreads();

  // ---- extract A fragments (xh, xl) into registers + ||x||^2 per q-row
  short8 xh[4], xl[4];
  float xx;
  {
    const int qloc = w * 32 + col;
    float s = 0.f;
#pragma unroll
    for (int kf = 0; kf < 4; ++kf) {
#pragma unroll
      for (int j = 0; j < 8; ++j) {
        const int d = kf * 16 + half * 8 + j;
        const float v = xfp[d * 128 + qloc];
        float rest, dump;
        xh[kf][j] = (short)bf16_rne(v, rest);
        xl[kf][j] = (short)bf16_rne(rest, dump);
        s += v * v;
      }
    }
    s += __shfl_xor(s, 32);  // lanes l, l^32 hold same q, complementary d
    xx = s;
  }
  __syncthreads();  // xfp dead; B double-buffer takes over smem

  float best[16];
  int meta[16];
#pragma unroll
  for (int r = 0; r < 16; ++r) { best[r] = -3.4e38f; meta[r] = 0; }

  // ---- stage one 16KB chunk (64 codes x 256B) via global_load_lds width=16
  auto stage = [&](int ch, int buf) {
    const float* src = packed + (size_t)ch * 4096 + w * 256 + l * 4;
    char* dstb = smem + buf * 16384 + w * 1024;  // wave-uniform LDS base
#pragma unroll
    for (int i = 0; i < 4; ++i) GLL16(src + i * 1024, dstb + i * 4096);
  };

  stage(0, 0);
  for (int ch = 0; ch < nch; ++ch) {
    __syncthreads();  // staged buf ready (barrier drains vmcnt); prev buf free
    if (ch + 1 < nch) stage(ch + 1, (ch + 1) & 1);
    const char* bufp = smem + (ch & 1) * 16384;

    // acc starts at -0.5||c||^2 (C layout: col = lane&31 for every reg)
    f32x16 acc[2];
    {
      const float nh0 = nhn[ch * 64 + col];
      const float nh1 = nhn[ch * 64 + 32 + col];
#pragma unroll
      for (int r = 0; r < 16; ++r) { acc[0][r] = nh0; acc[1][r] = nh1; }
    }

#pragma unroll
    for (int kf = 0; kf < 4; ++kf) {
      short8 bh[2], bl[2];
      const int gh = kf * 2 + half;  // hi granule; lo granule = gh + 8
#pragma unroll
      for (int n = 0; n < 2; ++n) {
        const char* rp = bufp + (n * 32 + col) * 256;
        bh[n] = *(const short8*)(rp + ((gh ^ sw) << 4));
        bl[n] = *(const short8*)(rp + (((gh + 8) ^ sw) << 4));
      }
#pragma unroll
      for (int n = 0; n < 2; ++n)
        acc[n] = __builtin_amdgcn_mfma_f32_32x32x16_bf16(xh[kf], bh[n], acc[n], 0, 0, 0);
#pragma unroll
      for (int n = 0; n < 2; ++n)
        acc[n] = __builtin_amdgcn_mfma_f32_32x32x16_bf16(xh[kf], bl[n], acc[n], 0, 0, 0);
#pragma unroll
      for (int n = 0; n < 2; ++n)
        acc[n] = __builtin_amdgcn_mfma_f32_32x32x16_bf16(xl[kf], bh[n], acc[n], 0, 0, 0);
    }

    // ---- running argmax; meta = ch*2 + nf (col implicit)
    const int mb = ch * 2;
#pragma unroll
    for (int r = 0; r < 16; ++r) {
      const float s0 = acc[0][r];
      const float s1 = acc[1][r];
      const bool t1 = s1 > s0;  // tie -> nf=0 (smaller index)
      const float v = t1 ? s1 : s0;
      const int mt = mb + (t1 ? 1 : 0);
      if (v > best[r]) { best[r] = v; meta[r] = mt; }  // tie -> earlier chunk
    }
  }

  // ---- cross-lane argmax reduce (within 32-lane half), first-index ties
  int* qidx = (int*)smem;  // [128]; B bufs fully consumed
  float ls = 0.f;
#pragma unroll
  for (int r = 0; r < 16; ++r) {
    float v = best[r];
    int idx = meta[r] * 32 + col;
#pragma unroll
    for (int mk = 1; mk < 32; mk <<= 1) {
      const float ov = __shfl_xor(v, mk);
      const int oi = __shfl_xor(idx, mk);
      if (ov > v || (ov == v && oi < idx)) { v = ov; idx = oi; }
    }
    const int row = (r & 3) + 8 * (r >> 2) + 4 * half;  // C layout row
    if (col == row) {
      ls += xx - 2.0f * v;  // ||x||^2 - 2(x.c* - 0.5||c*||^2) = ||x-c*||^2
      qidx[w * 32 + row] = idx;
    }
  }
#pragma unroll
  for (int mk = 1; mk < 64; mk <<= 1) ls += __shfl_xor(ls, mk);
  if (l == 0) atomicAdd(ws, ls);
  __syncthreads();

  // ---- histogram + quantized output (NCHW, coalesced stores; codes L2-hot)
  const int qloc = tid & 127;
  const int dh = tid >> 7;  // 0/1: which 32-d half this thread writes
  const int ci = qidx[qloc];
  if (tid < 128) atomicAdd(&counts[ci], 1.0f);
  const float* crow = (ci < 512) ? (cb0 + (size_t)ci * 64) : (cb1 + (size_t)(ci - 512) * 64);
  float cv[32];
#pragma unroll
  for (int d = 0; d < 32; d += 4) {
    const float4 f = *(const float4*)(crow + dh * 32 + d);
    cv[d] = f.x; cv[d + 1] = f.y; cv[d + 2] = f.z; cv[d + 3] = f.w;
  }
  float* ob = out + (((size_t)(bb * 64 + dh * 32)) << 12) + hw0 + qloc;
#pragma unroll
  for (int d = 0; d < 32; ++d) ob[(size_t)d << 12] = cv[d];
}

__global__ void vq_final(const float* __restrict__ ws, float* __restrict__ out) {
  __shared__ float sred[256];
  const int t = threadIdx.x;
  float h = 0.f;
#pragma unroll
  for (int i = t; i < 1024; i += 256) {
    const float avg = ws[2048 + i] * (1.0f / 131072.0f);
    h += avg * logf(avg + 1e-10f);
  }
  sred[t] = h;
  __syncthreads();
  for (int s2 = 128; s2 > 0; s2 >>= 1) {
    if (t < s2) sred[t] += sred[t + s2];
    __syncthreads();
  }
  if (t == 0) {
    out[8388608] = 1.25f * ws[0] * (1.0f / 8388608.0f);
    out[8388609] = expf(-sred[0]);
  }
}

extern "C" void kernel_launch(void* const* d_in, const int* in_sizes, int n_in,
                              void* d_out, int out_size, void* d_ws, size_t ws_size,
                              hipStream_t stream) {
  (void)in_sizes; (void)n_in; (void)out_size; (void)ws_size;
  const float* xin = (const float*)d_in[0];
  const float* cb0 = (const float*)d_in[1];
  const float* cb1 = (const float*)d_in[2];
  const int* idxp = (const int*)d_in[3];
  float* out = (float*)d_out;
  float* ws = (float*)d_ws;

  vq_pack<<<4, 256, 0, stream>>>(cb0, cb1, ws);
  vq_main<<<1024, 256, 0, stream>>>(xin, cb0, cb1, idxp, out, ws);
  vq_final<<<1, 256, 0, stream>>>(ws, out);
}